// Round 8
// baseline (194.062 us; speedup 1.0000x reference)
//
#include <hip/hip_runtime.h>

// KnotAttention MI355X — round 8: persistent blocks + double-buffered tile
// pipeline + register-resident (iter-invariant) weight fragments.
//
// R7 autopsy: 3125 short blocks each pay ~2k cy of serial prologue (nbr ->
// DMA -> barrier) with ~2.7 blocks/CU to hide it => ~75% stall. Fix:
// 1024 persistent blocks, 2x40KB LDS tile double-buffer (2 blocks/CU),
// next tile's gather DMAs issued at iter start (~2000 cy cover before the
// iter-end __syncthreads drain). A-fragments depend only on the head ->
// persist 4 mats in VGPRs, reload the 2 others per iter (same address
// every iter = L1-hot). k1 atomics hoisted out of the loop (block-local
// accumulation). k2 writes C directly in MFMA layout (float4, no LDS).

#define N_NODES 100000
#define D 128
#define H 4
#define R 5
#define NPB 32
#define NT 3125            // node tiles (100000 / 32, exact)
#define GRID 1024
#define THREADS 256
#define TILE_B 8192        // bytes per slot tile (32 rows x 256 B)
#define BUF_B (5 * TILE_B) // 40960

typedef _Float16 half_t;
typedef __attribute__((ext_vector_type(8))) _Float16 f16x8;
typedef __attribute__((ext_vector_type(4))) float f32x4;

typedef const __attribute__((address_space(1))) unsigned int* gp_t;
typedef __attribute__((address_space(3))) unsigned int* lp_t;

__device__ __forceinline__ void async_copy16(const void* g, void* l) {
    __builtin_amdgcn_global_load_lds((gp_t)g, (lp_t)l, 16, 0, 0);
}

struct NB { int4 a, b; };

__device__ __forceinline__ NB ld_nb(const int* __restrict__ nbr, int base, int tid) {
    int rowA = ((tid >> 6) << 2) + ((tid & 63) >> 4);
    NB nb;
    nb.a = ((const int4*)nbr)[base + rowA];
    nb.b = ((const int4*)nbr)[base + rowA + 16];
    return nb;
}

// stage all 5 slot-tiles of one 32-node tile (10 DMA instrs per wave).
// quad kq of row stored at kq^(row&7); swizzle folded into GLOBAL address,
// LDS dest is wave-uniform base + lane*16 (HW requirement).
__device__ __forceinline__ void stage_all(const half_t* __restrict__ xh, int base,
                                          const NB& nb, char* tile, int tid)
{
    const int w = tid >> 6, lane = tid & 63;
    const int rr = lane >> 4, c = lane & 15;
    const int rowA = (w << 2) + rr;
    int srcA[5] = {base + rowA, nb.a.x, nb.a.y, nb.a.z, nb.a.w};
    int srcB[5] = {base + rowA + 16, nb.b.x, nb.b.y, nb.b.z, nb.b.w};
    const int sw = ((c ^ (rowA & 7)) << 4);
#pragma unroll
    for (int s = 0; s < 5; ++s) {
        async_copy16((const char*)xh + (size_t)srcA[s] * 256 + sw,
                     tile + s * TILE_B + (w * 4) * 256);
        async_copy16((const char*)xh + (size_t)srcB[s] * 256 + sw,
                     tile + s * TILE_B + (w * 4 + 16) * 256);
    }
}

// ------------- prep: weights -> A-frags, x -> f16, zero sums_p --------------
__global__ void prep(const float* __restrict__ x,
                     const float* __restrict__ wq, const float* __restrict__ wk,
                     const float* __restrict__ wv,
                     half_t* __restrict__ xh, half_t* __restrict__ wph,
                     float* __restrict__ sums_p)
{
    const int bid = blockIdx.x;
    const int t = threadIdx.x;
    if (bid < 44) {
        const float* src = (bid < 4) ? (wq + bid * 4096)
                         : (bid < 24) ? (wk + (bid - 4) * 4096)
                                      : (wv + (bid - 24) * 4096);
#pragma unroll
        for (int i = 0; i < 16; ++i) {
            int p = t * 16 + i;
            int j = p & 7, ln = (p >> 3) & 63, f = p >> 9;
            int kt = f & 3, mt = f >> 2;
            int d = kt * 32 + (ln >> 4) * 8 + j;
            int ko = mt * 16 + (ln & 15);
            wph[bid * 4096 + p] = (half_t)src[d * 32 + ko];
        }
    } else {
        if (bid == 44) {
            for (int i = t; i < 1280; i += THREADS) sums_p[i] = 0.f;
        }
        const int total = N_NODES * D / 8;
        const int nb = gridDim.x - 44;
        for (int i = (bid - 44) * THREADS + t; i < total; i += nb * THREADS) {
            const float4* s = (const float4*)x + (size_t)i * 2;
            float4 a = s[0], b = s[1];
            f16x8 h8 = {(half_t)a.x, (half_t)a.y, (half_t)a.z, (half_t)a.w,
                        (half_t)b.x, (half_t)b.y, (half_t)b.z, (half_t)b.w};
            *((f16x8*)xh + i) = h8;
        }
    }
}

// --------------------- A-frag load: exactly 8 loads -------------------------
__device__ __forceinline__ void load_af(int mid, const half_t* __restrict__ wph,
                                        int lane, f16x8 (&af)[8])
{
#pragma unroll
    for (int kt = 0; kt < 4; ++kt) {
        af[kt * 2]     = *(const f16x8*)(wph + ((mid * 8 + kt) * 64 + lane) * 8);
        af[kt * 2 + 1] = *(const f16x8*)(wph + ((mid * 8 + 4 + kt) * 64 + lane) * 8);
    }
}

// -------- 32(kout) x 32(node) x 128(d) projection from LDS slot tile --------
__device__ __forceinline__ void proj32(const f16x8 (&af)[8], const half_t* tile,
                                       int lane, f32x4 (&acc)[2][2])
{
    const int l15 = lane & 15, q = lane >> 4;
#pragma unroll
    for (int mt = 0; mt < 2; ++mt)
#pragma unroll
        for (int nt = 0; nt < 2; ++nt)
            acc[mt][nt] = (f32x4){0.f, 0.f, 0.f, 0.f};
#pragma unroll
    for (int kt = 0; kt < 4; ++kt) {
#pragma unroll
        for (int nt = 0; nt < 2; ++nt) {
            int row = nt * 16 + l15;
            int sq = (kt * 4 + q) ^ (row & 7);
            f16x8 b = *(const f16x8*)(tile + row * 128 + sq * 8);
            acc[0][nt] = __builtin_amdgcn_mfma_f32_16x16x32_f16(af[kt * 2], b, acc[0][nt], 0, 0, 0);
            acc[1][nt] = __builtin_amdgcn_mfma_f32_16x16x32_f16(af[kt * 2 + 1], b, acc[1][nt], 0, 0, 0);
        }
    }
}

// fused: two projections sharing one B-read pass (slot0: Q and K0)
__device__ __forceinline__ void proj32_2(const f16x8 (&a0)[8], const f16x8 (&a1)[8],
                                         const half_t* tile, int lane,
                                         f32x4 (&c0)[2][2], f32x4 (&c1)[2][2])
{
    const int l15 = lane & 15, q = lane >> 4;
#pragma unroll
    for (int mt = 0; mt < 2; ++mt)
#pragma unroll
        for (int nt = 0; nt < 2; ++nt) {
            c0[mt][nt] = (f32x4){0.f, 0.f, 0.f, 0.f};
            c1[mt][nt] = (f32x4){0.f, 0.f, 0.f, 0.f};
        }
#pragma unroll
    for (int kt = 0; kt < 4; ++kt) {
#pragma unroll
        for (int nt = 0; nt < 2; ++nt) {
            int row = nt * 16 + l15;
            int sq = (kt * 4 + q) ^ (row & 7);
            f16x8 b = *(const f16x8*)(tile + row * 128 + sq * 8);
            c0[0][nt] = __builtin_amdgcn_mfma_f32_16x16x32_f16(a0[kt * 2], b, c0[0][nt], 0, 0, 0);
            c0[1][nt] = __builtin_amdgcn_mfma_f32_16x16x32_f16(a0[kt * 2 + 1], b, c0[1][nt], 0, 0, 0);
            c1[0][nt] = __builtin_amdgcn_mfma_f32_16x16x32_f16(a1[kt * 2], b, c1[0][nt], 0, 0, 0);
            c1[1][nt] = __builtin_amdgcn_mfma_f32_16x16x32_f16(a1[kt * 2 + 1], b, c1[1][nt], 0, 0, 0);
        }
    }
}

// --------------------------- kernel 1: Q,K -> e, sums ------------------------
#define LOGIT(r)                                                              \
    {   float es_ = 0.f;                                                      \
        _Pragma("unroll")                                                     \
        for (int nt = 0; nt < 2; ++nt) {                                      \
            float p_ = 0.f;                                                   \
            _Pragma("unroll")                                                 \
            for (int mt = 0; mt < 2; ++mt)                                    \
                _Pragma("unroll")                                             \
                for (int j = 0; j < 4; ++j)                                   \
                    p_ += qf[mt][nt][j] * kf[mt][nt][j];                      \
            p_ += __shfl_xor(p_, 16, 64);                                     \
            p_ += __shfl_xor(p_, 32, 64);                                     \
            float e_ = __expf(p_ * 0.17677669529663688f);                     \
            if (q == 0)                                                       \
                eh[(size_t)(h * 5 + (r)) * N_NODES + base + nt * 16 + l15] = (half_t)e_; \
            es_ += e_;                                                        \
        }                                                                     \
        es_ += __shfl_xor(es_, 1, 64); es_ += __shfl_xor(es_, 2, 64);         \
        es_ += __shfl_xor(es_, 4, 64); es_ += __shfl_xor(es_, 8, 64);         \
        esum_acc[r] += es_;                                                   \
    }

__global__ __launch_bounds__(THREADS, 2)
void knot_logits(const half_t* __restrict__ xh, const int* __restrict__ nbr,
                 const half_t* __restrict__ wph,
                 half_t* __restrict__ eh, float* __restrict__ sums_p)
{
    __shared__ __align__(16) char smem[2 * BUF_B];
    const int tid = threadIdx.x;
    const int lane = tid & 63;
    const int h = __builtin_amdgcn_readfirstlane((int)(tid >> 6));
    const int l15 = lane & 15, q = lane >> 4;

    // persistent (iter-invariant) A-fragments: Q, K0, K1, K2
    f16x8 aq[8], ak0[8], ak1[8], ak2[8];
    load_af(h, wph, lane, aq);
    load_af(4 + h * 5 + 0, wph, lane, ak0);
    load_af(4 + h * 5 + 1, wph, lane, ak1);
    load_af(4 + h * 5 + 2, wph, lane, ak2);

    float esum_acc[5] = {0.f, 0.f, 0.f, 0.f, 0.f};

    int t = blockIdx.x;
    char* cur = smem;
    char* nxt = smem + BUF_B;
    {
        NB nb0 = ld_nb(nbr, t * NPB, tid);
        stage_all(xh, t * NPB, nb0, cur, tid);
    }
    int tn = t + GRID;
    bool hasn = (tn < NT);
    NB nb_n;
    if (hasn) nb_n = ld_nb(nbr, tn * NPB, tid);
    __syncthreads();

#pragma unroll 1
    for (;;) {
        const int base = t * NPB;
        if (hasn) stage_all(xh, tn * NPB, nb_n, nxt, tid);   // ~full-iter cover
        const int tn2 = tn + GRID;
        if (tn2 < NT) nb_n = ld_nb(nbr, tn2 * NPB, tid);

        f16x8 pb[8];
        load_af(4 + h * 5 + 3, wph, lane, pb);               // K3 (L1-hot)

        f32x4 qf[2][2], kf[2][2];
        const half_t* tp = (const half_t*)cur;
        proj32_2(aq, ak0, tp, lane, qf, kf);                 // slot0: Q + K0
        LOGIT(0)
        proj32(ak1, (const half_t*)(cur + TILE_B), lane, kf);     LOGIT(1)
        proj32(ak2, (const half_t*)(cur + 2 * TILE_B), lane, kf); LOGIT(2)
        proj32(pb,  (const half_t*)(cur + 3 * TILE_B), lane, kf); LOGIT(3)
        load_af(4 + h * 5 + 4, wph, lane, pb);               // K4 (L1-hot)
        proj32(pb,  (const half_t*)(cur + 4 * TILE_B), lane, kf); LOGIT(4)

        if (!hasn) break;
        __syncthreads();            // drains next-tile DMAs (issued ~2k cy ago)
        { char* tmp = cur; cur = nxt; nxt = tmp; }
        t = tn; tn = tn2; hasn = (tn < NT);
    }

    // one atomic set per block (spread over 64 slots)
#pragma unroll
    for (int r = 0; r < R; ++r)
        if (lane == 0)
            atomicAdd(&sums_p[(h * 5 + r) * 64 + (blockIdx.x & 63)], esum_acc[r]);
}

// --------------------------- kernel 2: V -> Z -> out -------------------------
#define VACC(r)                                                               \
    _Pragma("unroll")                                                         \
    for (int nt = 0; nt < 2; ++nt) {                                          \
        float w_ = evc[r][nt] * inv[r];                                       \
        _Pragma("unroll")                                                     \
        for (int mt = 0; mt < 2; ++mt)                                        \
            z[mt][nt] += w_ * vf[mt][nt];                                     \
    }

__global__ __launch_bounds__(THREADS, 2)
void knot_out(const half_t* __restrict__ xh, const int* __restrict__ nbr,
              const half_t* __restrict__ wph, const half_t* __restrict__ eh,
              const float* __restrict__ sums_p, float* __restrict__ out)
{
    __shared__ __align__(16) char smem[2 * BUF_B];
    const int tid = threadIdx.x;
    const int lane = tid & 63;
    const int h = __builtin_amdgcn_readfirstlane((int)(tid >> 6));
    const int l15 = lane & 15, q = lane >> 4;

    // softmax sums: one 64-lane reduce per block (result broadcast to all lanes)
    float inv[5];
#pragma unroll
    for (int r = 0; r < R; ++r) {
        float v = sums_p[(h * 5 + r) * 64 + lane];
        v += __shfl_xor(v, 1, 64);  v += __shfl_xor(v, 2, 64);
        v += __shfl_xor(v, 4, 64);  v += __shfl_xor(v, 8, 64);
        v += __shfl_xor(v, 16, 64); v += __shfl_xor(v, 32, 64);
        inv[r] = 1.0f / v;
    }

    // persistent V-fragments: V0, V1, V2
    f16x8 av0[8], av1[8], av2[8];
    load_af(24 + h * 5 + 0, wph, lane, av0);
    load_af(24 + h * 5 + 1, wph, lane, av1);
    load_af(24 + h * 5 + 2, wph, lane, av2);

    int t = blockIdx.x;
    char* cur = smem;
    char* nxt = smem + BUF_B;
    {
        NB nb0 = ld_nb(nbr, t * NPB, tid);
        stage_all(xh, t * NPB, nb0, cur, tid);
    }
    int tn = t + GRID;
    bool hasn = (tn < NT);
    NB nb_n;
    if (hasn) nb_n = ld_nb(nbr, tn * NPB, tid);
    float evc[5][2];
#pragma unroll
    for (int r = 0; r < R; ++r)
#pragma unroll
        for (int nt = 0; nt < 2; ++nt)
            evc[r][nt] = (float)eh[(size_t)(h * 5 + r) * N_NODES + t * NPB + nt * 16 + l15];
    __syncthreads();

#pragma unroll 1
    for (;;) {
        const int base = t * NPB;
        if (hasn) stage_all(xh, tn * NPB, nb_n, nxt, tid);
        const int tn2 = tn + GRID;
        if (tn2 < NT) nb_n = ld_nb(nbr, tn2 * NPB, tid);

        float evn[5][2];
        if (hasn) {
#pragma unroll
            for (int r = 0; r < R; ++r)
#pragma unroll
                for (int nt = 0; nt < 2; ++nt)
                    evn[r][nt] = (float)eh[(size_t)(h * 5 + r) * N_NODES + tn * NPB + nt * 16 + l15];
        }

        f16x8 pb[8];
        load_af(24 + h * 5 + 3, wph, lane, pb);              // V3 (L1-hot)

        f32x4 z[2][2], vf[2][2];
        proj32(av0, (const half_t*)cur, lane, vf);
#pragma unroll
        for (int nt = 0; nt < 2; ++nt) {                     // init z at r=0
            float w_ = evc[0][nt] * inv[0];
#pragma unroll
            for (int mt = 0; mt < 2; ++mt)
                z[mt][nt] = w_ * vf[mt][nt];
        }
        proj32(av1, (const half_t*)(cur + TILE_B), lane, vf);     VACC(1)
        proj32(av2, (const half_t*)(cur + 2 * TILE_B), lane, vf); VACC(2)
        proj32(pb,  (const half_t*)(cur + 3 * TILE_B), lane, vf); VACC(3)
        load_af(24 + h * 5 + 4, wph, lane, pb);              // V4 (L1-hot)
        proj32(pb,  (const half_t*)(cur + 4 * TILE_B), lane, vf); VACC(4)

        // direct C-layout stores: lane (l15,q) owns out[node][h*32+mt*16+q*4..+3]
#pragma unroll
        for (int mt = 0; mt < 2; ++mt)
#pragma unroll
            for (int nt = 0; nt < 2; ++nt) {
                float* dst = out + (size_t)(base + nt * 16 + l15) * D
                           + h * 32 + mt * 16 + q * 4;
                *(float4*)dst = (float4){z[mt][nt][0], z[mt][nt][1],
                                         z[mt][nt][2], z[mt][nt][3]};
            }

        if (!hasn) break;
#pragma unroll
        for (int r = 0; r < R; ++r) {
            evc[r][0] = evn[r][0];
            evc[r][1] = evn[r][1];
        }
        __syncthreads();
        { char* tmp = cur; cur = nxt; nxt = tmp; }
        t = tn; tn = tn2; hasn = (tn < NT);
    }
}

// --------------------------------- launcher ---------------------------------
// ws (bytes): [0,5120) sums_p | [8192,+4e6) eh f16[20*N]
//             [4194304,+360448) wph | [4718592,+25.6e6) xh     ~30.3 MB
extern "C" void kernel_launch(void* const* d_in, const int* in_sizes, int n_in,
                              void* d_out, int out_size, void* d_ws, size_t ws_size,
                              hipStream_t stream)
{
    const float* x   = (const float*)d_in[0];
    const int*   nbr = (const int*)d_in[1];
    const float* w_q = (const float*)d_in[2];
    const float* w_k = (const float*)d_in[3];
    const float* w_v = (const float*)d_in[4];
    float* out = (float*)d_out;

    float*  sums_p = (float*)d_ws;
    half_t* eh     = (half_t*)((char*)d_ws + 8192);
    half_t* wph    = (half_t*)((char*)d_ws + 4194304);
    half_t* xh     = (half_t*)((char*)d_ws + 4718592);

    prep<<<44 + 2048, THREADS, 0, stream>>>(x, w_q, w_k, w_v, xh, wph, sums_p);
    knot_logits<<<GRID, THREADS, 0, stream>>>(xh, nbr, wph, eh, sums_p);
    knot_out<<<GRID, THREADS, 0, stream>>>(xh, nbr, wph, eh, sums_p, out);
}